// Round 3
// baseline (609.808 us; speedup 1.0000x reference)
//
#include <hip/hip_runtime.h>

namespace {

constexpr int Gg     = 160;
constexpr int NA     = 3;
constexpr int NB     = 16;
constexpr int CP     = 86;          // channels per anchor: 6 + 80
constexpr int PLANE  = Gg * Gg;     // 25600
constexpr int QPP    = PLANE / 4;   // 6400 quads per (b,a) plane
constexpr int TOTAL  = NB * NA * QPP;   // 307200 threads
constexpr float STRIDE = 8.0f;      // 1280 / 160

typedef float fvec4 __attribute__((ext_vector_type(4)));  // native vec: ok for nontemporal builtins

union F4 { fvec4 v; float f[4]; };

__device__ __forceinline__ fvec4 ld4(const float* p) {
    return *reinterpret_cast<const fvec4*>(p);
}

__device__ __forceinline__ float fsigmoid(float v) {
    // 1/(1+e^-v) with fast exp + hw rcp; abs threshold is ~135, this is safe.
    return __builtin_amdgcn_rcpf(1.0f + __expf(-v));
}

__global__ __launch_bounds__(256) void anchor_decode(
    const float* __restrict__ x,
    const float* __restrict__ anchors,
    float* __restrict__ out)
{
    const int t = blockIdx.x * 256 + threadIdx.x;

    const int q   = t % QPP;
    const int ba  = t / QPP;           // b*NA + a
    const int a   = ba % NA;
    const int pix = q * 4;
    const int gy  = pix / Gg;          // grid_y
    const int gx  = pix - gy * Gg;     // grid_x of first pixel (160 % 4 == 0)

    const float* xp = x + (size_t)ba * (size_t)CP * PLANE + pix;

    // ---- prologue loads: tree inits + 6 head channels (8 loads in flight) ----
    F4 vA, vB;                          // running max, even / odd class trees
    vA.v = ld4(xp + 6 * PLANE);         // class 0
    vB.v = ld4(xp + 7 * PLANE);         // class 1
    F4 c0, c1, c2, c3, c4, c5;
    c0.v = ld4(xp + 0 * PLANE);
    c1.v = ld4(xp + 1 * PLANE);
    c2.v = ld4(xp + 2 * PLANE);
    c3.v = ld4(xp + 3 * PLANE);
    c4.v = ld4(xp + 4 * PLANE);
    c5.v = ld4(xp + 5 * PLANE);

    float iA[4] = {0.f, 0.f, 0.f, 0.f};
    float iB[4] = {1.f, 1.f, 1.f, 1.f};

    // ---- class channels 2..79 as even/odd pairs: two independent select
    // trees, unroll 8 -> 16 loads in flight, no cross-tree dependency ----
    #pragma unroll 8
    for (int c = 2; c < 80; c += 2) {
        F4 uA, uB;
        uA.v = ld4(xp + (size_t)(6 + c) * PLANE);
        uB.v = ld4(xp + (size_t)(7 + c) * PLANE);
        #pragma unroll
        for (int p = 0; p < 4; ++p) {
            const bool gA = uA.f[p] > vA.f[p];
            vA.f[p] = gA ? uA.f[p] : vA.f[p];
            iA[p]   = gA ? (float)c : iA[p];
            const bool gB = uB.f[p] > vB.f[p];
            vB.f[p] = gB ? uB.f[p] : vB.f[p];
            iB[p]   = gB ? (float)(c + 1) : iB[p];
        }
    }

    const float aw = anchors[a * 2 + 0];
    const float ah = anchors[a * 2 + 1];
    const float fi = (float)gy;
    const float fj = (float)gx;

    alignas(16) float fout[28];
    #pragma unroll
    for (int p = 0; p < 4; ++p) {
        // merge trees with numpy first-occurrence tie-break
        const bool takeB = (vB.f[p] > vA.f[p]) ||
                           ((vB.f[p] == vA.f[p]) && (iB[p] < iA[p]));
        const float bidx = takeB ? iB[p] : iA[p];

        fout[p * 7 + 0] = floorf((fsigmoid(c0.f[p]) + (fj + (float)p)) * STRIDE);
        fout[p * 7 + 1] = floorf((fsigmoid(c1.f[p]) + fi) * STRIDE);
        fout[p * 7 + 2] = __expf(c2.f[p]) * aw;
        fout[p * 7 + 3] = __expf(c3.f[p]) * ah;
        fout[p * 7 + 4] = c4.f[p];
        fout[p * 7 + 5] = fsigmoid(c5.f[p]);
        fout[p * 7 + 6] = bidx;
    }

    // 28 contiguous floats, byte offset = (ba*PLANE+pix)*28, pix%4==0 -> 16B aligned.
    // Output is written once and never read: nontemporal (nt) stores.
    float* op = out + (size_t)(ba * PLANE + pix) * 7;
    #pragma unroll
    for (int k = 0; k < 7; ++k) {
        __builtin_nontemporal_store(
            *reinterpret_cast<const fvec4*>(&fout[k * 4]),
            reinterpret_cast<fvec4*>(op + k * 4));
    }
}

} // namespace

extern "C" void kernel_launch(void* const* d_in, const int* in_sizes, int n_in,
                              void* d_out, int out_size, void* d_ws, size_t ws_size,
                              hipStream_t stream) {
    (void)in_sizes; (void)n_in; (void)d_ws; (void)ws_size; (void)out_size;
    const float* x       = (const float*)d_in[0];
    // d_in[1] (target) is unused by the reference output
    const float* anchors = (const float*)d_in[2];
    float* out           = (float*)d_out;

    const int blocks = TOTAL / 256;  // 1200, exact
    anchor_decode<<<blocks, 256, 0, stream>>>(x, anchors, out);
}

// Round 4
// 562.160 us; speedup vs baseline: 1.0848x; 1.0848x over previous
//
#include <hip/hip_runtime.h>

namespace {

constexpr int Gg     = 160;
constexpr int NA     = 3;
constexpr int NB     = 16;
constexpr int CP     = 86;          // channels per anchor: 6 + 80
constexpr int PLANE  = Gg * Gg;     // 25600
constexpr int QPP    = PLANE / 4;   // 6400 quads per (b,a) plane
constexpr int TOTAL  = NB * NA * QPP;   // 307200 threads (1 quad each)
constexpr float STRIDE = 8.0f;      // 1280 / 160

typedef float fvec4 __attribute__((ext_vector_type(4)));

union F4 { fvec4 v; float f[4]; };

__device__ __forceinline__ fvec4 ld4(const float* p) {
    return *reinterpret_cast<const fvec4*>(p);
}

__device__ __forceinline__ float fsigmoid(float v) {
    // 1/(1+e^-v) with fast exp + hw rcp; abs threshold is ~135, this is safe.
    return __builtin_amdgcn_rcpf(1.0f + __expf(-v));
}

// One wave per block: fine-grained scheduling, no intra-block barriers needed.
__global__ __launch_bounds__(64) void anchor_decode(
    const float* __restrict__ x,
    const float* __restrict__ anchors,
    float* __restrict__ out)
{
    const int t = blockIdx.x * 64 + threadIdx.x;

    const int q   = t % QPP;
    const int ba  = t / QPP;           // b*NA + a
    const int a   = ba % NA;
    const int pix = q * 4;
    const int gy  = pix / Gg;          // grid_y
    const int gx  = pix - gy * Gg;     // grid_x of first pixel (160 % 4 == 0)

    const float* xp = x + (size_t)ba * (size_t)CP * PLANE + pix;

    // ---- head channels issued first (oldest in vmcnt queue -> retire first) ----
    F4 c0, c1, c2, c3, c4, c5;
    c0.v = ld4(xp + 0 * PLANE);
    c1.v = ld4(xp + 1 * PLANE);
    c2.v = ld4(xp + 2 * PLANE);
    c3.v = ld4(xp + 3 * PLANE);
    c4.v = ld4(xp + 4 * PLANE);
    c5.v = ld4(xp + 5 * PLANE);

    // ---- dual argmax trees (even / odd classes), unroll 4 pairs:
    //      8 class loads in flight, half-length select chains ----
    F4 vA, vB;
    vA.v = ld4(xp + 6 * PLANE);         // class 0
    vB.v = ld4(xp + 7 * PLANE);         // class 1
    float iA[4] = {0.f, 0.f, 0.f, 0.f};
    float iB[4] = {1.f, 1.f, 1.f, 1.f};

    #pragma unroll 4
    for (int c = 2; c < 80; c += 2) {
        F4 uA, uB;
        uA.v = ld4(xp + (size_t)(6 + c) * PLANE);
        uB.v = ld4(xp + (size_t)(7 + c) * PLANE);
        #pragma unroll
        for (int p = 0; p < 4; ++p) {
            const bool gA = uA.f[p] > vA.f[p];
            vA.f[p] = gA ? uA.f[p] : vA.f[p];
            iA[p]   = gA ? (float)c : iA[p];
            const bool gB = uB.f[p] > vB.f[p];
            vB.f[p] = gB ? uB.f[p] : vB.f[p];
            iB[p]   = gB ? (float)(c + 1) : iB[p];
        }
    }

    const float aw = anchors[a * 2 + 0];
    const float ah = anchors[a * 2 + 1];
    const float fi = (float)gy;
    const float fj = (float)gx;

    alignas(16) float fout[28];
    #pragma unroll
    for (int p = 0; p < 4; ++p) {
        // merge trees with numpy first-occurrence tie-break
        const bool takeB = (vB.f[p] > vA.f[p]) ||
                           ((vB.f[p] == vA.f[p]) && (iB[p] < iA[p]));
        const float bidx = takeB ? iB[p] : iA[p];

        fout[p * 7 + 0] = floorf((fsigmoid(c0.f[p]) + (fj + (float)p)) * STRIDE);
        fout[p * 7 + 1] = floorf((fsigmoid(c1.f[p]) + fi) * STRIDE);
        fout[p * 7 + 2] = __expf(c2.f[p]) * aw;
        fout[p * 7 + 3] = __expf(c3.f[p]) * ah;
        fout[p * 7 + 4] = c4.f[p];
        fout[p * 7 + 5] = fsigmoid(c5.f[p]);
        fout[p * 7 + 6] = bidx;
    }

    // 28 contiguous floats, byte offset = (ba*PLANE+pix)*28, pix%4==0 -> 16B aligned
    float* op = out + (size_t)(ba * PLANE + pix) * 7;
    #pragma unroll
    for (int k = 0; k < 7; ++k) {
        *reinterpret_cast<fvec4*>(op + k * 4) =
            *reinterpret_cast<const fvec4*>(&fout[k * 4]);
    }
}

} // namespace

extern "C" void kernel_launch(void* const* d_in, const int* in_sizes, int n_in,
                              void* d_out, int out_size, void* d_ws, size_t ws_size,
                              hipStream_t stream) {
    (void)in_sizes; (void)n_in; (void)d_ws; (void)ws_size; (void)out_size;
    const float* x       = (const float*)d_in[0];
    // d_in[1] (target) is unused by the reference output
    const float* anchors = (const float*)d_in[2];
    float* out           = (float*)d_out;

    const int blocks = TOTAL / 64;  // 4800 one-wave blocks, exact
    anchor_decode<<<blocks, 64, 0, stream>>>(x, anchors, out);
}